// Round 4
// baseline (361.542 us; speedup 1.0000x reference)
//
#include <hip/hip_runtime.h>
#include <math.h>

// RWKV-6 fully-fused chunked scan.  B=4 H=32 T=2048 K=V=64.
// Round 4: occupancy + critical-path round.
//   Grid 512 = (bh 0..127) x (v-quarter 0..3), 512 threads (8 waves),
//   ~53 KB LDS -> 2 blocks/CU (was 1), __launch_bounds__(512,4).
//   Waves 0-3 compute o-tiles, waves 4-7 compute S_c tiles + carry the
//   16v x 64k state slice (4 regs/thread on those waves).
//   d3 (diag) reduce batched: 8 products then 6 shuffle rounds x 8-wide ILP
//   (critical path 6 deep, was 48).
//   All LDS swizzles dropped: 144-byte row stride (9 x 16B) already spreads
//   b128 accesses uniformly over the 8 bank groups; KhT covers the old
//   column-gather.  Raw lgkmcnt-only barriers kept (prefetch stays in flight).
// Numerics identical to the verified kernel:
//   Qh = q*e^{cw_{t-1}-Cmid}, Kh = k*e^{Cmid-cw_s}  (Cmid = cw_31)
//   Qt = q*e^{cw_{t-1}};  A-diag = q*u*k;  S_c scaled by e^{tot-Cmid} per-k;
//   h = h*e^{tot} + S_c.

#define Bdim 4
#define Hdim 32
#define Tdim 2048
#define Kdim 64
#define Vdim 64
#define NC   32
#define CL   64
#define LP   72   // padded LDS row stride (bf16 elems): 144 B = 9 x 16 B

typedef __attribute__((ext_vector_type(8))) short short8;
typedef __attribute__((ext_vector_type(4))) float float4_;

__device__ __forceinline__ short f2bf(float x) {
    unsigned u = __float_as_uint(x);
    unsigned r = (u + 0x7FFFu + ((u >> 16) & 1u)) >> 16;
    return (short)r;
}

#define MFMA(a, b, c) __builtin_amdgcn_mfma_f32_16x16x32_bf16(a, b, c, 0, 0, 0)

// Barrier WITHOUT the vmcnt(0) drain __syncthreads emits: LDS producer
// visibility only; global prefetch loads stay in flight across it.
__device__ __forceinline__ void wg_barrier() {
    __builtin_amdgcn_sched_barrier(0);
    asm volatile("s_waitcnt lgkmcnt(0)");
    __builtin_amdgcn_s_barrier();
    __builtin_amdgcn_sched_barrier(0);
}

__global__ __launch_bounds__(512, 4) void rwkv6_fused(
    const float* __restrict__ rin, const float* __restrict__ kin,
    const float* __restrict__ vin, const float* __restrict__ win,
    const float* __restrict__ uin, const float* __restrict__ init,
    float* __restrict__ oout, float* __restrict__ fin)
{
    __shared__ __attribute__((aligned(16))) short Qh[CL * LP];
    __shared__ __attribute__((aligned(16))) short Kh[CL * LP];   // row-major [s][k]
    __shared__ __attribute__((aligned(16))) short KhT[CL * LP];  // transposed [k][s]
    __shared__ __attribute__((aligned(16))) short Qt[CL * LP];
    __shared__ __attribute__((aligned(16))) short Am[CL * LP];
    __shared__ __attribute__((aligned(16))) short Vt[16 * LP];   // V^T[v_local][s]
    __shared__ __attribute__((aligned(16))) short Ht[16 * LP];   // h0^T[v_local][k]
    __shared__ float bsum[8 * 64];
    __shared__ float Dd[CL];

    const int tid  = threadIdx.x;
    const int wv   = tid >> 6;          // wave 0..7
    const int lane = tid & 63;          // k index in preprocessing
    const int quad = lane >> 4, r = lane & 15;

    const int bid = blockIdx.x;
    const int vq  = bid >> 7;           // v-quarter 0..3 (siblings 128 apart -> same XCD)
    const int bh  = bid & 127;
    const int h_idx = bh & (Hdim - 1);

    const int k_  = 16 * (wv & 3) + r;  // S_c role: k column (waves 4-7)

    const float u_ = uin[h_idx * Kdim + lane];

    // V staging: thread owns v-row svrow, 2 consecutive s-cols
    const int svrow = tid & 15;         // v_local 0..15
    const int st2   = tid >> 4;         // 0..31 -> s cols 2*st2, 2*st2+1

    // ---- pre-loop: zero Am (upper triangle stays 0), init h + Ht (waves 4-7) ----
    for (int i = tid; i < CL * LP; i += 512) Am[i] = 0;

    float h[4] = {0.f, 0.f, 0.f, 0.f};
    if (wv >= 4) {
#pragma unroll
        for (int reg = 0; reg < 4; ++reg) {
            const int vloc = quad * 4 + reg;
            h[reg] = init[((size_t)bh * Kdim + k_) * Vdim + 16 * vq + vloc];
            Ht[vloc * LP + k_] = f2bf(h[reg]);
        }
    }

    // register prefetch of chunk 0 (order: w, v first -- pass1 consumers)
    float wl[8], ql[8], kl[8], vls[2];
    {
        const size_t b0 = (size_t)bh * Tdim * Kdim;
#pragma unroll
        for (int tt = 0; tt < 8; ++tt) wl[tt] = win[b0 + (8 * wv + tt) * Kdim + lane];
#pragma unroll
        for (int i = 0; i < 2; ++i)
            vls[i] = vin[b0 + (2 * st2 + i) * Kdim + 16 * vq + svrow];
#pragma unroll
        for (int tt = 0; tt < 8; ++tt) ql[tt] = rin[b0 + (8 * wv + tt) * Kdim + lane];
#pragma unroll
        for (int tt = 0; tt < 8; ++tt) kl[tt] = kin[b0 + (8 * wv + tt) * Kdim + lane];
    }

    // A-phase tile helper (i >= j lower-triangle tiles)
    auto atile = [&](int i, int j) {
        const int trow = 16 * i + r;
        short8 qa0 = *(const short8*)&Qh[trow * LP + quad * 8];
        short8 qa1 = *(const short8*)&Qh[trow * LP + 32 + quad * 8];
        const int srow = 16 * j + r;
        short8 kb0 = *(const short8*)&Kh[srow * LP + quad * 8];
        short8 kb1 = *(const short8*)&Kh[srow * LP + 32 + quad * 8];
        float4_ acc = {0.f, 0.f, 0.f, 0.f};
        acc = MFMA(qa0, kb0, acc);
        acc = MFMA(qa1, kb1, acc);
#pragma unroll
        for (int reg = 0; reg < 4; ++reg) {
            const int tg = 16 * i + quad * 4 + reg;
            const float val = (tg > srow) ? acc[reg] : ((tg == srow) ? Dd[tg] : 0.f);
            Am[tg * LP + srow] = f2bf(val);
        }
    };

    float4_ sc;                 // S_c accumulator (waves 4-7)
    float totk = 0.f, cmk = 0.f;

    for (int c = 0; c < NC; ++c) {
        const size_t base = ((size_t)bh * Tdim + (size_t)c * CL) * Kdim;

        // ---- pass 1: block-sums of w, V staging (packed b32) ----
        float wreg[8];
        float cwl = 0.f;
#pragma unroll
        for (int tt = 0; tt < 8; ++tt) { wreg[tt] = wl[tt]; cwl += wl[tt]; }
        bsum[wv * 64 + lane] = cwl;
        {
            const unsigned p0 = (unsigned short)f2bf(vls[0]);
            const unsigned p1 = (unsigned short)f2bf(vls[1]);
            *(unsigned*)&Vt[svrow * LP + st2 * 2] = p0 | (p1 << 16);
        }
        wg_barrier();                                           // B1: bsum/Vt ready

        // ---- pass 2: prefix sums, Qh/Kh/KhT/Qt, batched Dd ----
        float b[8];
#pragma unroll
        for (int j = 0; j < 8; ++j) b[j] = bsum[j * 64 + lane];
        float pref = 0.f;
#pragma unroll
        for (int j = 0; j < 8; ++j) if (j < wv) pref += b[j];
        const float Cmid = b[0] + b[1] + b[2] + b[3];            // cw_31
        const float eC = __expf(Cmid);
        float cwrun = pref;                                      // cw_{t-1} entering block
        short8 khrow;                                            // KhT[k=lane][8wv..8wv+7]
        float d3p[8];
#pragma unroll
        for (int tt = 0; tt < 8; ++tt) {
            const int t = 8 * wv + tt;
            const float cwp = cwrun;                             // cw_{t-1}
            cwrun += wreg[tt];                                   // cw_t
            const float e1 = __expf(cwp - Cmid);
            Qh[t * LP + lane] = f2bf(ql[tt] * e1);
            Qt[t * LP + lane] = f2bf(ql[tt] * e1 * eC);          // q*e^{cw_{t-1}}
            const float e2 = __expf(Cmid - cwrun);
            const short kv = f2bf(kl[tt] * e2);
            Kh[t * LP + lane] = kv;
            khrow[tt] = kv;
            d3p[tt] = ql[tt] * u_ * kl[tt];
        }
        *(short8*)&KhT[lane * LP + wv * 8] = khrow;              // transposed b128 write
        // batched 64-lane reduce: 6 rounds, 8-wide ILP each
#pragma unroll
        for (int off = 32; off > 0; off >>= 1) {
#pragma unroll
            for (int tt = 0; tt < 8; ++tt) d3p[tt] += __shfl_xor(d3p[tt], off);
        }
        if (lane == 0) {
#pragma unroll
            for (int tt = 0; tt < 8; ++tt) Dd[8 * wv + tt] = d3p[tt];
        }
        // issue next-chunk loads; raw barriers keep them in flight until use
        if (c + 1 < NC) {
            const size_t nb = base + (size_t)CL * Kdim;
#pragma unroll
            for (int tt = 0; tt < 8; ++tt) wl[tt] = win[nb + (8 * wv + tt) * Kdim + lane];
#pragma unroll
            for (int i = 0; i < 2; ++i)
                vls[i] = vin[nb + (2 * st2 + i) * Kdim + 16 * vq + svrow];
#pragma unroll
            for (int tt = 0; tt < 8; ++tt) ql[tt] = rin[nb + (8 * wv + tt) * Kdim + lane];
#pragma unroll
            for (int tt = 0; tt < 8; ++tt) kl[tt] = kin[nb + (8 * wv + tt) * Kdim + lane];
        }
        wg_barrier();                                           // B2: Qh/Kh/KhT/Qt/Dd ready

        // ---- A-phase: 10 lower-triangle tiles over 8 waves ----
        {
            int i0, j0;
            if (wv == 0)      { i0 = 0; j0 = 0; }
            else if (wv < 3)  { i0 = 1; j0 = wv - 1; }
            else if (wv < 6)  { i0 = 2; j0 = wv - 3; }
            else              { i0 = 3; j0 = wv - 6; }
            atile(i0, j0);
            if (wv < 2) atile(3, 2 + wv);                        // tiles (3,2),(3,3)
        }
        wg_barrier();                                           // B3: Am ready

        if (wv < 4) {
            // ---- o-phase (waves 0-3): o = Am.V + Qt.h0, t-tile = wv ----
            const int trow = 16 * wv + r;
            short8 aa0 = *(const short8*)&Am[trow * LP + quad * 8];
            short8 aa1 = *(const short8*)&Am[trow * LP + 32 + quad * 8];
            short8 qt0 = *(const short8*)&Qt[trow * LP + quad * 8];
            short8 qt1 = *(const short8*)&Qt[trow * LP + 32 + quad * 8];
            short8 vb0 = *(const short8*)&Vt[r * LP + quad * 8];
            short8 vb1 = *(const short8*)&Vt[r * LP + 32 + quad * 8];
            short8 hb0 = *(const short8*)&Ht[r * LP + quad * 8];
            short8 hb1 = *(const short8*)&Ht[r * LP + 32 + quad * 8];
            float4_ o4 = {0.f, 0.f, 0.f, 0.f};
            o4 = MFMA(aa0, vb0, o4);
            o4 = MFMA(aa1, vb1, o4);
            o4 = MFMA(qt0, hb0, o4);
            o4 = MFMA(qt1, hb1, o4);
            float* op = oout + base;
#pragma unroll
            for (int reg = 0; reg < 4; ++reg)
                op[(16 * wv + quad * 4 + reg) * Vdim + 16 * vq + r] = o4[reg];
        } else {
            // ---- S_c (waves 4-7): D[v][k] = sum_s V[s][v]*Khat[s][k] ----
            short8 va0 = *(const short8*)&Vt[r * LP + quad * 8];
            short8 va1 = *(const short8*)&Vt[r * LP + 32 + quad * 8];
            short8 kc0 = *(const short8*)&KhT[k_ * LP + quad * 8];
            short8 kc1 = *(const short8*)&KhT[k_ * LP + 32 + quad * 8];
            sc = (float4_){0.f, 0.f, 0.f, 0.f};
            sc = MFMA(va0, kc0, sc);
            sc = MFMA(va1, kc1, sc);
            // per-k chunk totals (bsum stable until pass1(c+1), after B4)
            totk = 0.f; cmk = 0.f;
#pragma unroll
            for (int j = 0; j < 8; ++j) {
                const float bb = bsum[j * 64 + k_];
                totk += bb;
                if (j < 4) cmk += bb;
            }
        }
        wg_barrier();                                           // B4: all LDS reads done

        // ---- state update + bf16 copy for next chunk (waves 4-7) ----
        if (wv >= 4) {
            const float eA = __expf(totk);                       // e^{cw_63}
            const float eS = __expf(totk - cmk);                 // Khat-acc -> Kbar-acc
#pragma unroll
            for (int reg = 0; reg < 4; ++reg) {
                h[reg] = h[reg] * eA + sc[reg] * eS;
                Ht[(quad * 4 + reg) * LP + k_] = f2bf(h[reg]);
            }
        }
        // next iteration's B1 orders Ht writes before o-phase reads
    }

    // ---- final state (waves 4-7) ----
    if (wv >= 4) {
#pragma unroll
        for (int reg = 0; reg < 4; ++reg)
            fin[((size_t)bh * Kdim + k_) * Vdim + 16 * vq + quad * 4 + reg] = h[reg];
    }
}

extern "C" void kernel_launch(void* const* d_in, const int* in_sizes, int n_in,
                              void* d_out, int out_size, void* d_ws, size_t ws_size,
                              hipStream_t stream) {
    const float* r    = (const float*)d_in[0];
    const float* k    = (const float*)d_in[1];
    const float* v    = (const float*)d_in[2];
    const float* w    = (const float*)d_in[3];
    const float* u    = (const float*)d_in[4];
    const float* init = (const float*)d_in[5];

    float* o   = (float*)d_out;
    float* fin = o + (size_t)Bdim * Hdim * Tdim * Vdim;

    (void)d_ws; (void)ws_size;
    rwkv6_fused<<<Bdim * Hdim * 4, 512, 0, stream>>>(r, k, v, w, u, init, o, fin);
}

// Round 5
// 292.397 us; speedup vs baseline: 1.2365x; 1.2365x over previous
//
#include <hip/hip_runtime.h>
#include <math.h>

// RWKV-6 fully-fused chunked scan.  B=4 H=32 T=2048 K=V=64.
// Round 5: revert to round-3 shape (256 blocks = bh x v-half, 512 thr, 1/CU)
// and software-pipeline chunks c|c+1 into a TWO-barrier loop:
//   SEG1: pass1(c+1) [w-sums, V staging]      || A-tiles(c) [MFMA]
//   SEG2: pass2(c+1) [exp, Q/K staging, Dd]   || prefetch(c+2)
//         || o(c)+S_c(c) [MFMA] || state update
// Barriers 128 -> 66; each segment mixes VMEM/LDS/VALU/MFMA from independent
// chunks so latencies overlap.  Double-buffered: Qh, KhT, Vt, Ht, bsum.
// Single: Kh (write a-separated from read), Am, Dd.
// Qt eliminated: o's h0-term uses Qh * (Ht' = h * e^{Cmid[k]}) -- identical
// product q*e^{cw_{t-1}}*h, saves 8 stores + 18 KB LDS.
// s_setprio(1) wraps MFMA clusters (T5; segments have role diversity now).
// Numerics identical to the verified kernel:
//   Qh = q*e^{cw_{t-1}-Cmid}, Kh = k*e^{Cmid-cw_s}  (Cmid = cw_31)
//   A-diag = q*u*k;  S_c scaled by e^{tot-Cmid} per-k;  h = h*e^{tot} + S_c.

#define Bdim 4
#define Hdim 32
#define Tdim 2048
#define Kdim 64
#define Vdim 64
#define NC   32
#define CL   64
#define LP   72   // padded LDS row stride (bf16): 144 B = 9 x 16 B (bank-uniform b128)

typedef __attribute__((ext_vector_type(8))) short short8;
typedef __attribute__((ext_vector_type(4))) short short4_;
typedef __attribute__((ext_vector_type(4))) float float4_;

__device__ __forceinline__ short f2bf(float x) {
    unsigned u = __float_as_uint(x);
    unsigned r = (u + 0x7FFFu + ((u >> 16) & 1u)) >> 16;
    return (short)r;
}

#define MFMA(a, b, c) __builtin_amdgcn_mfma_f32_16x16x32_bf16(a, b, c, 0, 0, 0)

// Barrier WITHOUT the vmcnt(0) drain __syncthreads emits: LDS producer
// visibility only; global prefetch loads stay in flight across it.
__device__ __forceinline__ void wg_barrier() {
    __builtin_amdgcn_sched_barrier(0);
    asm volatile("s_waitcnt lgkmcnt(0)");
    __builtin_amdgcn_s_barrier();
    __builtin_amdgcn_sched_barrier(0);
}

__global__ __launch_bounds__(512) void rwkv6_fused(
    const float* __restrict__ rin, const float* __restrict__ kin,
    const float* __restrict__ vin, const float* __restrict__ win,
    const float* __restrict__ uin, const float* __restrict__ init,
    float* __restrict__ oout, float* __restrict__ fin)
{
    __shared__ __attribute__((aligned(16))) short Qh[2][CL * LP];
    __shared__ __attribute__((aligned(16))) short Kh[CL * LP];      // [s][k], single
    __shared__ __attribute__((aligned(16))) short KhT[2][CL * LP];  // [k][s]
    __shared__ __attribute__((aligned(16))) short Am[CL * LP];      // single
    __shared__ __attribute__((aligned(16))) short Vt[2][32 * LP];   // V^T[v_local][s]
    __shared__ __attribute__((aligned(16))) short Ht[2][32 * LP];   // (h*e^{Cmid})^T[v][k]
    __shared__ float bsum[2][8 * 64];
    __shared__ float Dd[CL];

    const int tid  = threadIdx.x;
    const int wv   = tid >> 6;          // wave 0..7
    const int lane = tid & 63;          // k index in preprocessing
    const int quad = lane >> 4, r = lane & 15;

    const int bid = blockIdx.x;
    const int vh  = bid >> 7;           // v-half 0/1 (siblings 128 apart -> same XCD)
    const int bh  = bid & 127;
    const int h_idx = bh & (Hdim - 1);

    // S_c/state mapping: wave -> (v-tile m_s, k-tile n_s)
    const int m_s = wv >> 2;            // 0..1
    const int n_s = wv & 3;             // 0..3
    const int k_  = 16 * n_s + r;       // this thread's k column of the state
    // o-phase mapping: wave -> (t-tile i_o, v-tile n_o)
    const int i_o = wv >> 1;            // 0..3
    const int n_o = wv & 1;             // 0..1

    const float u_ = uin[h_idx * Kdim + lane];

    // V staging: thread owns v-row svrow, 4 consecutive s-cols
    const int svrow = tid & 31;         // v_local 0..31
    const int skq   = tid >> 5;         // 0..15 -> s cols 4*skq .. 4*skq+3

    // ---- zero Am (upper triangle stays 0 forever) ----
    for (int i = tid; i < CL * LP; i += 512) Am[i] = 0;

    // prefetch registers
    float wl[8], ql[8], kl[8], vls[4];

    auto do_prefetch = [&](size_t nb) {
#pragma unroll
        for (int tt = 0; tt < 8; ++tt) wl[tt] = win[nb + (8 * wv + tt) * Kdim + lane];
#pragma unroll
        for (int i = 0; i < 4; ++i)
            vls[i] = vin[nb + (4 * skq + i) * Kdim + 32 * vh + svrow];
#pragma unroll
        for (int tt = 0; tt < 8; ++tt) ql[tt] = rin[nb + (8 * wv + tt) * Kdim + lane];
#pragma unroll
        for (int tt = 0; tt < 8; ++tt) kl[tt] = kin[nb + (8 * wv + tt) * Kdim + lane];
    };

    auto do_pass1 = [&](int Y) {        // consumes wl, vls of chunk Y's data
        float cwl = 0.f;
#pragma unroll
        for (int tt = 0; tt < 8; ++tt) cwl += wl[tt];
        bsum[Y][wv * 64 + lane] = cwl;
        short4_ pack;
#pragma unroll
        for (int i = 0; i < 4; ++i) pack[i] = f2bf(vls[i]);
        *(short4_*)&Vt[Y][svrow * LP + 4 * skq] = pack;
    };

    auto do_pass2 = [&](int Y) {        // consumes wl, ql, kl; writes Qh[Y],Kh,KhT[Y],Dd
        float b8[8];
#pragma unroll
        for (int j = 0; j < 8; ++j) b8[j] = bsum[Y][j * 64 + lane];
        float pref = 0.f;
#pragma unroll
        for (int j = 0; j < 8; ++j) if (j < wv) pref += b8[j];
        const float Cmid = b8[0] + b8[1] + b8[2] + b8[3];        // cw_31
        float cwrun = pref;                                      // cw_{t-1} entering block
        short8 khrow;
        float d3p[8];
#pragma unroll
        for (int tt = 0; tt < 8; ++tt) {
            const int t = 8 * wv + tt;
            const float cwp = cwrun;                             // cw_{t-1}
            cwrun += wl[tt];                                     // cw_t
            Qh[Y][t * LP + lane] = f2bf(ql[tt] * __expf(cwp - Cmid));
            const short kv = f2bf(kl[tt] * __expf(Cmid - cwrun));
            Kh[t * LP + lane] = kv;
            khrow[tt] = kv;
            d3p[tt] = ql[tt] * u_ * kl[tt];
        }
        *(short8*)&KhT[Y][lane * LP + wv * 8] = khrow;           // transposed b128
        // batched 64-lane reduce: 6 rounds, 8-wide ILP
#pragma unroll
        for (int off = 32; off > 0; off >>= 1) {
#pragma unroll
            for (int tt = 0; tt < 8; ++tt) d3p[tt] += __shfl_xor(d3p[tt], off);
        }
        if (lane == 0) {
#pragma unroll
            for (int tt = 0; tt < 8; ++tt) Dd[8 * wv + tt] = d3p[tt];
        }
    };

    auto atile = [&](int X, int i, int j) {
        const int trow = 16 * i + r;
        short8 qa0 = *(const short8*)&Qh[X][trow * LP + quad * 8];
        short8 qa1 = *(const short8*)&Qh[X][trow * LP + 32 + quad * 8];
        const int srow = 16 * j + r;
        short8 kb0 = *(const short8*)&Kh[srow * LP + quad * 8];
        short8 kb1 = *(const short8*)&Kh[srow * LP + 32 + quad * 8];
        float4_ acc = {0.f, 0.f, 0.f, 0.f};
        acc = MFMA(qa0, kb0, acc);
        acc = MFMA(qa1, kb1, acc);
#pragma unroll
        for (int reg = 0; reg < 4; ++reg) {
            const int tg = 16 * i + quad * 4 + reg;
            const float val = (tg > srow) ? acc[reg] : ((tg == srow) ? Dd[tg] : 0.f);
            Am[tg * LP + srow] = f2bf(val);
        }
    };

    // ================= prologue =================
    const size_t bh_base = (size_t)bh * Tdim * Kdim;
    do_prefetch(bh_base);                       // chunk 0
    do_pass1(0);
    wg_barrier();
    do_pass2(0);
    float h[4];
    {   // h init + Ht[0] = init * e^{Cmid(0)}
        const float cm0 = bsum[0][0 * 64 + k_] + bsum[0][64 + k_]
                        + bsum[0][128 + k_] + bsum[0][192 + k_];
        const float eH = __expf(cm0);
#pragma unroll
        for (int reg = 0; reg < 4; ++reg) {
            const int vloc = 16 * m_s + quad * 4 + reg;
            h[reg] = init[((size_t)bh * Kdim + k_) * Vdim + 32 * vh + vloc];
            Ht[0][vloc * LP + k_] = f2bf(h[reg] * eH);
        }
    }
    do_prefetch(bh_base + (size_t)CL * Kdim);   // chunk 1
    wg_barrier();

    // ================= main loop: 2 barriers/chunk =================
    for (int c = 0; c < NC; ++c) {
        const int X = c & 1, Y = X ^ 1;
        const size_t base = bh_base + (size_t)c * CL * Kdim;

        // ---- SEG1: pass1(c+1) || A-tiles(c) ----
        if (c + 1 < NC) do_pass1(Y);
        __builtin_amdgcn_s_setprio(1);
        {
            int i0, j0;
            if (wv == 0)      { i0 = 0; j0 = 0; }
            else if (wv < 3)  { i0 = 1; j0 = wv - 1; }
            else if (wv < 6)  { i0 = 2; j0 = wv - 3; }
            else              { i0 = 3; j0 = wv - 6; }
            atile(X, i0, j0);
            if (wv < 2) atile(X, 3, 2 + wv);                    // tiles (3,2),(3,3)
        }
        __builtin_amdgcn_s_setprio(0);
        wg_barrier();                                           // alpha: Am/bsum[Y]/Vt[Y] ready

        // ---- SEG2: pass2(c+1) || prefetch(c+2) || o(c)+S_c(c) || state ----
        if (c + 1 < NC) do_pass2(Y);
        if (c + 2 < NC) do_prefetch(bh_base + (size_t)(c + 2) * CL * Kdim);

        __builtin_amdgcn_s_setprio(1);
        {   // o-phase: o = Am.V + Qh.Ht'  (wave -> t-tile i_o, v-tile n_o)
            const int trow = 16 * i_o + r;
            short8 aa0 = *(const short8*)&Am[trow * LP + quad * 8];
            short8 aa1 = *(const short8*)&Am[trow * LP + 32 + quad * 8];
            short8 qh0 = *(const short8*)&Qh[X][trow * LP + quad * 8];
            short8 qh1 = *(const short8*)&Qh[X][trow * LP + 32 + quad * 8];
            const int vrow = 16 * n_o + r;
            short8 vb0 = *(const short8*)&Vt[X][vrow * LP + quad * 8];
            short8 vb1 = *(const short8*)&Vt[X][vrow * LP + 32 + quad * 8];
            short8 hb0 = *(const short8*)&Ht[X][vrow * LP + quad * 8];
            short8 hb1 = *(const short8*)&Ht[X][vrow * LP + 32 + quad * 8];
            float4_ o4 = {0.f, 0.f, 0.f, 0.f};
            o4 = MFMA(aa0, vb0, o4);
            o4 = MFMA(aa1, vb1, o4);
            o4 = MFMA(qh0, hb0, o4);
            o4 = MFMA(qh1, hb1, o4);
            float* op = oout + base;
#pragma unroll
            for (int reg = 0; reg < 4; ++reg)
                op[(16 * i_o + quad * 4 + reg) * Vdim + 32 * vh + 16 * n_o + r] = o4[reg];
        }
        float4_ sc = {0.f, 0.f, 0.f, 0.f};
        {   // S_c: D[v][k] = sum_s V[s][v]*Khat[s][k]  (wave -> m_s, n_s)
            const int vrow = 16 * m_s + r;
            short8 va0 = *(const short8*)&Vt[X][vrow * LP + quad * 8];
            short8 va1 = *(const short8*)&Vt[X][vrow * LP + 32 + quad * 8];
            short8 kc0 = *(const short8*)&KhT[X][k_ * LP + quad * 8];
            short8 kc1 = *(const short8*)&KhT[X][k_ * LP + 32 + quad * 8];
            sc = MFMA(va0, kc0, sc);
            sc = MFMA(va1, kc1, sc);
        }
        __builtin_amdgcn_s_setprio(0);

        // ---- state update ----
        {
            float totk = 0.f, cmk = 0.f;
#pragma unroll
            for (int j = 0; j < 8; ++j) {
                const float bb = bsum[X][j * 64 + k_];
                totk += bb;
                if (j < 4) cmk += bb;
            }
            const float eA = __expf(totk);                       // e^{cw_63}
            const float eS = __expf(totk - cmk);                 // Khat-acc -> Kbar-acc
#pragma unroll
            for (int reg = 0; reg < 4; ++reg)
                h[reg] = h[reg] * eA + sc[reg] * eS;
            if (c + 1 < NC) {                                    // Ht' for chunk c+1
                const float cm1 = bsum[Y][0 * 64 + k_] + bsum[Y][64 + k_]
                                + bsum[Y][128 + k_] + bsum[Y][192 + k_];
                const float eH = __expf(cm1);
#pragma unroll
                for (int reg = 0; reg < 4; ++reg)
                    Ht[Y][(16 * m_s + quad * 4 + reg) * LP + k_] = f2bf(h[reg] * eH);
            }
        }
        wg_barrier();                                           // beta
    }

    // ---- final state ----
#pragma unroll
    for (int reg = 0; reg < 4; ++reg)
        fin[((size_t)bh * Kdim + k_) * Vdim + 32 * vh + 16 * m_s + quad * 4 + reg] = h[reg];
}

extern "C" void kernel_launch(void* const* d_in, const int* in_sizes, int n_in,
                              void* d_out, int out_size, void* d_ws, size_t ws_size,
                              hipStream_t stream) {
    const float* r    = (const float*)d_in[0];
    const float* k    = (const float*)d_in[1];
    const float* v    = (const float*)d_in[2];
    const float* w    = (const float*)d_in[3];
    const float* u    = (const float*)d_in[4];
    const float* init = (const float*)d_in[5];

    float* o   = (float*)d_out;
    float* fin = o + (size_t)Bdim * Hdim * Tdim * Vdim;

    (void)d_ws; (void)ws_size;
    rwkv6_fused<<<Bdim * Hdim * 2, 512, 0, stream>>>(r, k, v, w, u, init, o, fin);
}